// Round 9
// baseline (313.465 us; speedup 1.0000x reference)
//
#include <hip/hip_runtime.h>
#include <hip/hip_bf16.h>
#include <math.h>

// x: (2, 192, 256, 256) f32 ; w_qkv: (192, 576) ; b_qkv: (576,)
// windows: 32x32 = 1024 per batch, 8x8=64 pixels each
// out: (2, 1024, 4, 64, 192) f32
#define NB   2
#define NC   192
#define HW   256
#define NWIN 1024
#define SHW  64
#define NDQ  192
#define WCOL 576

typedef short bf16x8 __attribute__((ext_vector_type(8)));
typedef float f32x4  __attribute__((ext_vector_type(4)));

__device__ inline unsigned int bf16pack(float a, float b) {
  unsigned int ua = __builtin_bit_cast(unsigned int, a);
  ua += 0x7fffu + ((ua >> 16) & 1u);
  unsigned int ub = __builtin_bit_cast(unsigned int, b);
  ub += 0x7fffu + ((ub >> 16) & 1u);
  return (ua >> 16) | (ub & 0xffff0000u);
}

__device__ inline unsigned short bf16r(float a) {
  unsigned int ua = __builtin_bit_cast(unsigned int, a);
  ua += 0x7fffu + ((ua >> 16) & 1u);
  return (unsigned short)(ua >> 16);
}

// ---------------- K1: window mean of x -> xmean ; tail blocks build WvT bf16 ----------------
__global__ __launch_bounds__(256) void k1_mean(const float* __restrict__ x,
                                               float* __restrict__ xmean,
                                               const float* __restrict__ w,
                                               unsigned short* __restrict__ wvt) {
  if (blockIdx.x >= 1536) {
    int id = (blockIdx.x - 1536) * 256 + threadIdx.x;   // 192*192 = 36864
    if (id < NC * NC) {
      int d = id / NC, c = id - d * NC;
      wvt[d * NC + c] = bf16r(w[c * WCOL + 2 * NDQ + d]);
    }
    return;
  }
  int id = blockIdx.x * 256 + threadIdx.x;
  int n  = id & 1023;
  int c  = (id >> 10) % NC;
  int b  = id / (NC * NWIN);
  int wh = n >> 5, ww = n & 31;
  const float* p = x + (((size_t)(b * NC + c) * HW + wh * 8) * HW + ww * 8);
  double s = 0.0;
#pragma unroll
  for (int r = 0; r < 8; ++r) {
    float4 a = *(const float4*)(p + r * HW);
    float4 q = *(const float4*)(p + r * HW + 4);
    s += (double)a.x + a.y + a.z + a.w + q.x + q.y + q.z + q.w;
  }
  xmean[(size_t)(b * NWIN + n) * NC + c] = (float)(s * (1.0 / 64.0));
}

// ---------------- K2: 8-row tiles, 384 threads (thread d = w column d) ----------------
__global__ __launch_bounds__(384) void k2_qk(const float* __restrict__ xmean,
                                             const float* __restrict__ w,
                                             const float* __restrict__ bias,
                                             float* __restrict__ qw,
                                             float* __restrict__ kwT) {
  int b = blockIdx.y, n0 = blockIdx.x * 8;
  int d = threadIdx.x;   // 0..383 ; w column index directly (q: 0..191, k: 192..383)
  __shared__ float xs[8][NC];
#pragma unroll
  for (int i = 0; i < 4; ++i) {
    int l = i * 384 + d;
    int r = l / NC, c = l - r * NC;
    xs[r][c] = xmean[(size_t)(b * NWIN + n0 + r) * NC + c];
  }
  __syncthreads();

  double a[8];
#pragma unroll
  for (int r = 0; r < 8; ++r) a[r] = 0.0;
  for (int c = 0; c < NC; ++c) {
    double wv = (double)w[c * WCOL + d];
#pragma unroll
    for (int r = 0; r < 8; ++r) a[r] += (double)xs[r][c] * wv;
  }

  const float scale = 0.0721687836487032f;
  float bv = bias[d];
  if (d < NDQ) {
#pragma unroll
    for (int r = 0; r < 8; ++r)
      qw[(size_t)(b * NWIN + n0 + r) * NC + d] = ((float)a[r] + bv) * scale;
  } else {
#pragma unroll
    for (int r = 0; r < 8; ++r)
      kwT[(size_t)b * NC * NWIN + (size_t)(d - NDQ) * NWIN + n0 + r] = (float)a[r] + bv;
  }
}

// ---------------- K3: 8 logit rows per block (512 thr), per-wave top-4 ----------------
__global__ __launch_bounds__(512) void k3_topk(const float* __restrict__ qw,
                                               const float* __restrict__ kwT,
                                               int* __restrict__ topk) {
  int b = blockIdx.y, n0 = blockIdx.x * 8;
  int t = threadIdx.x;
  __shared__ float qs[8][NC];
  __shared__ float lg[8][NWIN];
#pragma unroll
  for (int i = 0; i < 3; ++i) {
    int l = i * 512 + t;
    int r = l / NC, c = l - r * NC;
    qs[r][c] = qw[(size_t)(b * NWIN + n0 + r) * NC + c];
  }
  __syncthreads();

  double acc[8][2];
#pragma unroll
  for (int r = 0; r < 8; ++r) { acc[r][0] = 0.0; acc[r][1] = 0.0; }

  const float* kb = kwT + (size_t)b * NC * NWIN;
#pragma unroll 2
  for (int c = 0; c < NC; ++c) {
    float2 kv = *(const float2*)(kb + (size_t)c * NWIN + t * 2);
    double k0 = (double)kv.x, k1 = (double)kv.y;
#pragma unroll
    for (int r = 0; r < 8; ++r) {
      double q = (double)qs[r][c];
      acc[r][0] += q * k0;
      acc[r][1] += q * k1;
    }
  }
#pragma unroll
  for (int r = 0; r < 8; ++r) {
    lg[r][t * 2]     = (float)acc[r][0];
    lg[r][t * 2 + 1] = (float)acc[r][1];
  }
  __syncthreads();

  int wave = t >> 6, lane = t & 63;
  int r = wave;  // 8 waves, one row each
  float v4[4];
  int   i4[4];
#pragma unroll
  for (int j = 0; j < 4; ++j) { v4[j] = -INFINITY; i4[j] = 0x7fffffff; }
  for (int i = 0; i < 16; ++i) {
    int idx = i * 64 + lane;
    float v = lg[r][idx];
    if (v > v4[3] || (v == v4[3] && idx < i4[3])) {
      v4[3] = v; i4[3] = idx;
#pragma unroll
      for (int j = 3; j > 0; --j) {
        if (v4[j] > v4[j-1] || (v4[j] == v4[j-1] && i4[j] < i4[j-1])) {
          float tv = v4[j]; v4[j] = v4[j-1]; v4[j-1] = tv;
          int ti = i4[j]; i4[j] = i4[j-1]; i4[j-1] = ti;
        }
      }
    }
  }
  for (int m = 1; m < 64; m <<= 1) {
    float ov[4]; int oi[4];
#pragma unroll
    for (int j = 0; j < 4; ++j) { ov[j] = __shfl_xor(v4[j], m); oi[j] = __shfl_xor(i4[j], m); }
    float nv[4]; int ni[4];
    int ia = 0, ib = 0;
#pragma unroll
    for (int j = 0; j < 4; ++j) {
      bool ta = (v4[ia] > ov[ib]) || (v4[ia] == ov[ib] && i4[ia] < oi[ib]);
      if (ta) { nv[j] = v4[ia]; ni[j] = i4[ia]; ++ia; }
      else    { nv[j] = ov[ib]; ni[j] = oi[ib]; ++ib; }
    }
#pragma unroll
    for (int j = 0; j < 4; ++j) { v4[j] = nv[j]; i4[j] = ni[j]; }
  }
  if (lane == 0) {
    int n = n0 + r;
#pragma unroll
    for (int k = 0; k < 4; ++k)
      topk[(size_t)(b * NWIN + n) * 4 + k] = i4[k];
  }
}

// ---------------- KA: MFMA bf16 V-GEMM for ALL windows -> Vtmp bf16 (L3-resident) ----------------
__global__ __launch_bounds__(1024) void kA_vgemm(const float* __restrict__ x,
                                                 const unsigned short* __restrict__ wvt,
                                                 const float* __restrict__ bias,
                                                 unsigned short* __restrict__ vtmp) {
  int b = blockIdx.y, g = blockIdx.x;   // g in [0,256)
  int m0 = g * 4;
  int wh = m0 >> 5, ww0 = m0 & 31;
  int t = threadIdx.x;

  __shared__ unsigned short Xs[16384];  // 32 KB: 4 win * 64 p * 128B

  int L = t & 63, wv = t >> 6;
  int win = wv >> 2, dq = wv & 3;
  int col = L & 15, kg = L >> 4;

  f32x4 acc[4][3];
#pragma unroll
  for (int dt = 0; dt < 3; ++dt) {
    float bv = bias[2 * NDQ + dq * 48 + dt * 16 + col];
    f32x4 bi = {bv, bv, bv, bv};
#pragma unroll
    for (int pt = 0; pt < 4; ++pt) acc[pt][dt] = bi;
  }

  int cp = t & 15, gi = t >> 4;
  int r = gi >> 3, w4 = gi & 7;
  int winS = w4 >> 1;
  int pS = r * 8 + (w4 & 1) * 4;
  const float* xb = x + (size_t)(b * NC) * (HW * HW) + (size_t)(wh * 8 + r) * HW + ww0 * 8 + w4 * 4;

  for (int cc = 0; cc < 6; ++cc) {
    const float* pl = xb + (size_t)(cc * 32 + cp * 2) * (HW * HW);
    float4 va = *(const float4*)pl;
    float4 vb = *(const float4*)(pl + HW * HW);
    float fa[4] = {va.x, va.y, va.z, va.w};
    float fb[4] = {vb.x, vb.y, vb.z, vb.w};
#pragma unroll
    for (int i = 0; i < 4; ++i) {
      int p = pS + i;
      unsigned int pk = bf16pack(fa[i], fb[i]);
      *(unsigned int*)((char*)Xs + (winS * 8192 + p * 128 + ((cp * 4) ^ ((p & 7) << 4)))) = pk;
    }
    __syncthreads();

    bf16x8 Bf[3];
#pragma unroll
    for (int dt = 0; dt < 3; ++dt)
      Bf[dt] = *(const bf16x8*)(wvt + (size_t)(dq * 48 + dt * 16 + col) * NC + cc * 32 + kg * 8);

#pragma unroll
    for (int pt = 0; pt < 4; ++pt) {
      int p = pt * 16 + col;
      bf16x8 Af = *(const bf16x8*)((const char*)Xs +
                    (win * 8192 + p * 128 + ((kg * 16) ^ ((p & 7) << 4))));
      acc[pt][0] = __builtin_amdgcn_mfma_f32_16x16x32_bf16(Af, Bf[0], acc[pt][0], 0, 0, 0);
      acc[pt][1] = __builtin_amdgcn_mfma_f32_16x16x32_bf16(Af, Bf[1], acc[pt][1], 0, 0, 0);
      acc[pt][2] = __builtin_amdgcn_mfma_f32_16x16x32_bf16(Af, Bf[2], acc[pt][2], 0, 0, 0);
    }
    __syncthreads();
  }

  unsigned short* dst = vtmp + (size_t)(b * NWIN + m0 + win) * (SHW * NC) + dq * 48 + col;
#pragma unroll
  for (int pt = 0; pt < 4; ++pt) {
#pragma unroll
    for (int rr = 0; rr < 4; ++rr) {
      unsigned short* dp = dst + (size_t)(pt * 16 + kg * 4 + rr) * NC;
      dp[0]  = bf16r(acc[pt][0][rr]);
      dp[16] = bf16r(acc[pt][1][rr]);
      dp[32] = bf16r(acc[pt][2][rr]);
    }
  }
}

// ---------------- KB: gather+convert out[slot] = f32(Vtmp[b, topk[slot]]), nt stores ----------------
__global__ __launch_bounds__(256) void kB_gather(const unsigned short* __restrict__ vtmp,
                                                 const int* __restrict__ topk,
                                                 float* __restrict__ out) {
  int id = blockIdx.x;            // 8192 = b*4096 + n*4 + k
  int b = id >> 12;
  int m = topk[id];
  const unsigned short* src = vtmp + (size_t)(b * NWIN + m) * (SHW * NC);
  float* dst = out + (size_t)id * (SHW * NC);
  int t = threadIdx.x;
#pragma unroll
  for (int i = 0; i < 6; ++i) {
    int u = i * 256 + t;          // 1536 units of 8 bf16
    uint4 v = *(const uint4*)(src + u * 8);
    f32x4 a, c;
    a.x = __builtin_bit_cast(float, v.x << 16);
    a.y = __builtin_bit_cast(float, v.x & 0xffff0000u);
    a.z = __builtin_bit_cast(float, v.y << 16);
    a.w = __builtin_bit_cast(float, v.y & 0xffff0000u);
    c.x = __builtin_bit_cast(float, v.z << 16);
    c.y = __builtin_bit_cast(float, v.z & 0xffff0000u);
    c.z = __builtin_bit_cast(float, v.w << 16);
    c.w = __builtin_bit_cast(float, v.w & 0xffff0000u);
    __builtin_nontemporal_store(a, (f32x4*)(dst + u * 8));
    __builtin_nontemporal_store(c, (f32x4*)(dst + u * 8 + 4));
  }
}

extern "C" void kernel_launch(void* const* d_in, const int* in_sizes, int n_in,
                              void* d_out, int out_size, void* d_ws, size_t ws_size,
                              hipStream_t stream) {
  const float* x    = (const float*)d_in[0];
  const float* w    = (const float*)d_in[1];
  const float* bias = (const float*)d_in[2];
  float* out = (float*)d_out;

  unsigned short* vtmp = (unsigned short*)d_ws;          // 2*1024*64*192 bf16 = 50 MB
  float* xmean = (float*)(vtmp + (size_t)25165824);      // 2*1024*192
  float* qw    = xmean + 393216;
  float* kwT   = qw + 393216;
  int*   topk  = (int*)(kwT + 393216);                   // 2*1024*4
  unsigned short* wvt = (unsigned short*)(topk + 8192);  // 192*192 bf16

  k1_mean<<<1680, 256, 0, stream>>>(x, xmean, w, wvt);
  k2_qk<<<dim3(128, 2), 384, 0, stream>>>(xmean, w, bias, qw, kwT);
  k3_topk<<<dim3(128, 2), 512, 0, stream>>>(qw, kwT, topk);
  kA_vgemm<<<dim3(256, 2), 1024, 0, stream>>>(x, wvt, bias, vtmp);
  kB_gather<<<8192, 256, 0, stream>>>(vtmp, topk, out);
}

// Round 10
// 283.417 us; speedup vs baseline: 1.1060x; 1.1060x over previous
//
#include <hip/hip_runtime.h>
#include <hip/hip_bf16.h>
#include <math.h>

// x: (2, 192, 256, 256) f32 ; w_qkv: (192, 576) ; b_qkv: (576,)
// windows: 32x32 = 1024 per batch, 8x8=64 pixels each
// out: (2, 1024, 4, 64, 192) f32
#define NB   2
#define NC   192
#define HW   256
#define NWIN 1024
#define SHW  64
#define NDQ  192
#define WCOL 576

typedef short bf16x8 __attribute__((ext_vector_type(8)));
typedef float f32x4  __attribute__((ext_vector_type(4)));

__device__ inline unsigned int bf16pack(float a, float b) {
  unsigned int ua = __builtin_bit_cast(unsigned int, a);
  ua += 0x7fffu + ((ua >> 16) & 1u);
  unsigned int ub = __builtin_bit_cast(unsigned int, b);
  ub += 0x7fffu + ((ub >> 16) & 1u);
  return (ua >> 16) | (ub & 0xffff0000u);
}

__device__ inline unsigned short bf16r(float a) {
  unsigned int ua = __builtin_bit_cast(unsigned int, a);
  ua += 0x7fffu + ((ua >> 16) & 1u);
  return (unsigned short)(ua >> 16);
}

// ---------------- K1: window mean of x -> xmean ; tail blocks build WvT bf16 ----------------
__global__ __launch_bounds__(256) void k1_mean(const float* __restrict__ x,
                                               float* __restrict__ xmean,
                                               const float* __restrict__ w,
                                               unsigned short* __restrict__ wvt) {
  if (blockIdx.x >= 1536) {
    int id = (blockIdx.x - 1536) * 256 + threadIdx.x;   // 192*192 = 36864
    if (id < NC * NC) {
      int d = id / NC, c = id - d * NC;
      wvt[d * NC + c] = bf16r(w[c * WCOL + 2 * NDQ + d]);
    }
    return;
  }
  int id = blockIdx.x * 256 + threadIdx.x;
  int n  = id & 1023;
  int c  = (id >> 10) % NC;
  int b  = id / (NC * NWIN);
  int wh = n >> 5, ww = n & 31;
  const float* p = x + (((size_t)(b * NC + c) * HW + wh * 8) * HW + ww * 8);
  double s = 0.0;
#pragma unroll
  for (int r = 0; r < 8; ++r) {
    float4 a = *(const float4*)(p + r * HW);
    float4 q = *(const float4*)(p + r * HW + 4);
    s += (double)a.x + a.y + a.z + a.w + q.x + q.y + q.z + q.w;
  }
  xmean[(size_t)(b * NWIN + n) * NC + c] = (float)(s * (1.0 / 64.0));
}

// ---------------- K2: 8-row tiles, 384 threads (thread d = w column d) ----------------
__global__ __launch_bounds__(384) void k2_qk(const float* __restrict__ xmean,
                                             const float* __restrict__ w,
                                             const float* __restrict__ bias,
                                             float* __restrict__ qw,
                                             float* __restrict__ kwT) {
  int b = blockIdx.y, n0 = blockIdx.x * 8;
  int d = threadIdx.x;   // 0..383 ; w column index directly (q: 0..191, k: 192..383)
  __shared__ float xs[8][NC];
#pragma unroll
  for (int i = 0; i < 4; ++i) {
    int l = i * 384 + d;
    int r = l / NC, c = l - r * NC;
    xs[r][c] = xmean[(size_t)(b * NWIN + n0 + r) * NC + c];
  }
  __syncthreads();

  double a[8];
#pragma unroll
  for (int r = 0; r < 8; ++r) a[r] = 0.0;
  for (int c = 0; c < NC; ++c) {
    double wv = (double)w[c * WCOL + d];
#pragma unroll
    for (int r = 0; r < 8; ++r) a[r] += (double)xs[r][c] * wv;
  }

  const float scale = 0.0721687836487032f;
  float bv = bias[d];
  if (d < NDQ) {
#pragma unroll
    for (int r = 0; r < 8; ++r)
      qw[(size_t)(b * NWIN + n0 + r) * NC + d] = ((float)a[r] + bv) * scale;
  } else {
#pragma unroll
    for (int r = 0; r < 8; ++r)
      kwT[(size_t)b * NC * NWIN + (size_t)(d - NDQ) * NWIN + n0 + r] = (float)a[r] + bv;
  }
}

// ---------------- K3: 8 logit rows per block (512 thr), per-wave top-4 ----------------
__global__ __launch_bounds__(512) void k3_topk(const float* __restrict__ qw,
                                               const float* __restrict__ kwT,
                                               int* __restrict__ topk) {
  int b = blockIdx.y, n0 = blockIdx.x * 8;
  int t = threadIdx.x;
  __shared__ float qs[8][NC];
  __shared__ float lg[8][NWIN];
#pragma unroll
  for (int i = 0; i < 3; ++i) {
    int l = i * 512 + t;
    int r = l / NC, c = l - r * NC;
    qs[r][c] = qw[(size_t)(b * NWIN + n0 + r) * NC + c];
  }
  __syncthreads();

  double acc[8][2];
#pragma unroll
  for (int r = 0; r < 8; ++r) { acc[r][0] = 0.0; acc[r][1] = 0.0; }

  const float* kb = kwT + (size_t)b * NC * NWIN;
#pragma unroll 2
  for (int c = 0; c < NC; ++c) {
    float2 kv = *(const float2*)(kb + (size_t)c * NWIN + t * 2);
    double k0 = (double)kv.x, k1 = (double)kv.y;
#pragma unroll
    for (int r = 0; r < 8; ++r) {
      double q = (double)qs[r][c];
      acc[r][0] += q * k0;
      acc[r][1] += q * k1;
    }
  }
#pragma unroll
  for (int r = 0; r < 8; ++r) {
    lg[r][t * 2]     = (float)acc[r][0];
    lg[r][t * 2 + 1] = (float)acc[r][1];
  }
  __syncthreads();

  int wave = t >> 6, lane = t & 63;
  int r = wave;  // 8 waves, one row each
  float v4[4];
  int   i4[4];
#pragma unroll
  for (int j = 0; j < 4; ++j) { v4[j] = -INFINITY; i4[j] = 0x7fffffff; }
  for (int i = 0; i < 16; ++i) {
    int idx = i * 64 + lane;
    float v = lg[r][idx];
    if (v > v4[3] || (v == v4[3] && idx < i4[3])) {
      v4[3] = v; i4[3] = idx;
#pragma unroll
      for (int j = 3; j > 0; --j) {
        if (v4[j] > v4[j-1] || (v4[j] == v4[j-1] && i4[j] < i4[j-1])) {
          float tv = v4[j]; v4[j] = v4[j-1]; v4[j-1] = tv;
          int ti = i4[j]; i4[j] = i4[j-1]; i4[j-1] = ti;
        }
      }
    }
  }
  for (int m = 1; m < 64; m <<= 1) {
    float ov[4]; int oi[4];
#pragma unroll
    for (int j = 0; j < 4; ++j) { ov[j] = __shfl_xor(v4[j], m); oi[j] = __shfl_xor(i4[j], m); }
    float nv[4]; int ni[4];
    int ia = 0, ib = 0;
#pragma unroll
    for (int j = 0; j < 4; ++j) {
      bool ta = (v4[ia] > ov[ib]) || (v4[ia] == ov[ib] && i4[ia] < oi[ib]);
      if (ta) { nv[j] = v4[ia]; ni[j] = i4[ia]; ++ia; }
      else    { nv[j] = ov[ib]; ni[j] = oi[ib]; ++ib; }
    }
#pragma unroll
    for (int j = 0; j < 4; ++j) { v4[j] = nv[j]; i4[j] = ni[j]; }
  }
  if (lane == 0) {
    int n = n0 + r;
#pragma unroll
    for (int k = 0; k < 4; ++k)
      topk[(size_t)(b * NWIN + n) * 4 + k] = i4[k];
  }
}

// ---------------- KA: MFMA bf16 V-GEMM for ALL windows -> Vtmp bf16 (L3-resident) ----------------
__global__ __launch_bounds__(1024) void kA_vgemm(const float* __restrict__ x,
                                                 const unsigned short* __restrict__ wvt,
                                                 const float* __restrict__ bias,
                                                 unsigned short* __restrict__ vtmp) {
  int b = blockIdx.y, g = blockIdx.x;   // g in [0,256)
  int m0 = g * 4;
  int wh = m0 >> 5, ww0 = m0 & 31;
  int t = threadIdx.x;

  __shared__ unsigned short Xs[16384];  // 32 KB: 4 win * 64 p * 128B

  int L = t & 63, wv = t >> 6;
  int win = wv >> 2, dq = wv & 3;
  int col = L & 15, kg = L >> 4;

  f32x4 acc[4][3];
#pragma unroll
  for (int dt = 0; dt < 3; ++dt) {
    float bv = bias[2 * NDQ + dq * 48 + dt * 16 + col];
    f32x4 bi = {bv, bv, bv, bv};
#pragma unroll
    for (int pt = 0; pt < 4; ++pt) acc[pt][dt] = bi;
  }

  int cp = t & 15, gi = t >> 4;
  int r = gi >> 3, w4 = gi & 7;
  int winS = w4 >> 1;
  int pS = r * 8 + (w4 & 1) * 4;
  const float* xb = x + (size_t)(b * NC) * (HW * HW) + (size_t)(wh * 8 + r) * HW + ww0 * 8 + w4 * 4;

  for (int cc = 0; cc < 6; ++cc) {
    const float* pl = xb + (size_t)(cc * 32 + cp * 2) * (HW * HW);
    float4 va = *(const float4*)pl;
    float4 vb = *(const float4*)(pl + HW * HW);
    float fa[4] = {va.x, va.y, va.z, va.w};
    float fb[4] = {vb.x, vb.y, vb.z, vb.w};
#pragma unroll
    for (int i = 0; i < 4; ++i) {
      int p = pS + i;
      unsigned int pk = bf16pack(fa[i], fb[i]);
      *(unsigned int*)((char*)Xs + (winS * 8192 + p * 128 + ((cp * 4) ^ ((p & 7) << 4)))) = pk;
    }
    __syncthreads();

    bf16x8 Bf[3];
#pragma unroll
    for (int dt = 0; dt < 3; ++dt)
      Bf[dt] = *(const bf16x8*)(wvt + (size_t)(dq * 48 + dt * 16 + col) * NC + cc * 32 + kg * 8);

#pragma unroll
    for (int pt = 0; pt < 4; ++pt) {
      int p = pt * 16 + col;
      bf16x8 Af = *(const bf16x8*)((const char*)Xs +
                    (win * 8192 + p * 128 + ((kg * 16) ^ ((p & 7) << 4))));
      acc[pt][0] = __builtin_amdgcn_mfma_f32_16x16x32_bf16(Af, Bf[0], acc[pt][0], 0, 0, 0);
      acc[pt][1] = __builtin_amdgcn_mfma_f32_16x16x32_bf16(Af, Bf[1], acc[pt][1], 0, 0, 0);
      acc[pt][2] = __builtin_amdgcn_mfma_f32_16x16x32_bf16(Af, Bf[2], acc[pt][2], 0, 0, 0);
    }
    __syncthreads();
  }

  unsigned short* dst = vtmp + (size_t)(b * NWIN + m0 + win) * (SHW * NC) + dq * 48 + col;
#pragma unroll
  for (int pt = 0; pt < 4; ++pt) {
#pragma unroll
    for (int rr = 0; rr < 4; ++rr) {
      unsigned short* dp = dst + (size_t)(pt * 16 + kg * 4 + rr) * NC;
      dp[0]  = bf16r(acc[pt][0][rr]);
      dp[16] = bf16r(acc[pt][1][rr]);
      dp[32] = bf16r(acc[pt][2][rr]);
    }
  }
}

// ---------------- KB: gather+convert out[slot] = f32(Vtmp[b, topk[slot]]) ----------------
__global__ __launch_bounds__(256) void kB_gather(const unsigned short* __restrict__ vtmp,
                                                 const int* __restrict__ topk,
                                                 float* __restrict__ out) {
  int id = blockIdx.x;            // 8192 = b*4096 + n*4 + k
  int b = id >> 12;
  int m = topk[id];
  const unsigned short* src = vtmp + (size_t)(b * NWIN + m) * (SHW * NC);
  float* dst = out + (size_t)id * (SHW * NC);
  int t = threadIdx.x;
#pragma unroll
  for (int i = 0; i < 6; ++i) {
    int u = i * 256 + t;          // 1536 units of 8 bf16
    uint4 v = *(const uint4*)(src + u * 8);
    float4 a, c;
    a.x = __builtin_bit_cast(float, v.x << 16);
    a.y = __builtin_bit_cast(float, v.x & 0xffff0000u);
    a.z = __builtin_bit_cast(float, v.y << 16);
    a.w = __builtin_bit_cast(float, v.y & 0xffff0000u);
    c.x = __builtin_bit_cast(float, v.z << 16);
    c.y = __builtin_bit_cast(float, v.z & 0xffff0000u);
    c.z = __builtin_bit_cast(float, v.w << 16);
    c.w = __builtin_bit_cast(float, v.w & 0xffff0000u);
    *(float4*)(dst + u * 8)     = a;
    *(float4*)(dst + u * 8 + 4) = c;
  }
}

extern "C" void kernel_launch(void* const* d_in, const int* in_sizes, int n_in,
                              void* d_out, int out_size, void* d_ws, size_t ws_size,
                              hipStream_t stream) {
  const float* x    = (const float*)d_in[0];
  const float* w    = (const float*)d_in[1];
  const float* bias = (const float*)d_in[2];
  float* out = (float*)d_out;

  unsigned short* vtmp = (unsigned short*)d_ws;          // 2*1024*64*192 bf16 = 50 MB
  float* xmean = (float*)(vtmp + (size_t)25165824);      // 2*1024*192
  float* qw    = xmean + 393216;
  float* kwT   = qw + 393216;
  int*   topk  = (int*)(kwT + 393216);                   // 2*1024*4
  unsigned short* wvt = (unsigned short*)(topk + 8192);  // 192*192 bf16

  k1_mean<<<1680, 256, 0, stream>>>(x, xmean, w, wvt);
  k2_qk<<<dim3(128, 2), 384, 0, stream>>>(xmean, w, bias, qw, kwT);
  k3_topk<<<dim3(128, 2), 512, 0, stream>>>(qw, kwT, topk);
  kA_vgemm<<<dim3(256, 2), 1024, 0, stream>>>(x, wvt, bias, vtmp);
  kB_gather<<<8192, 256, 0, stream>>>(vtmp, topk, out);
}

// Round 11
// 232.235 us; speedup vs baseline: 1.3498x; 1.2204x over previous
//
#include <hip/hip_runtime.h>
#include <hip/hip_bf16.h>
#include <math.h>

// x: (2, 192, 256, 256) f32 ; w_qkv: (192, 576) ; b_qkv: (576,)
// windows: 32x32 = 1024 per batch, 8x8=64 pixels each
// out: (2, 1024, 4, 64, 192) f32
#define NB   2
#define NC   192
#define HW   256
#define NWIN 1024
#define SHW  64
#define NDQ  192
#define WCOL 576

typedef short bf16x8 __attribute__((ext_vector_type(8)));
typedef float f32x4  __attribute__((ext_vector_type(4)));

__device__ inline unsigned int bf16pack(float a, float b) {
  unsigned int ua = __builtin_bit_cast(unsigned int, a);
  ua += 0x7fffu + ((ua >> 16) & 1u);
  unsigned int ub = __builtin_bit_cast(unsigned int, b);
  ub += 0x7fffu + ((ub >> 16) & 1u);
  return (ua >> 16) | (ub & 0xffff0000u);
}

__device__ inline unsigned short bf16r(float a) {
  unsigned int ua = __builtin_bit_cast(unsigned int, a);
  ua += 0x7fffu + ((ua >> 16) & 1u);
  return (unsigned short)(ua >> 16);
}

// ---------------- K0: precompute WvT bf16 [d][c] ----------------
__global__ __launch_bounds__(256) void k0_wvt(const float* __restrict__ w,
                                              unsigned short* __restrict__ wvt) {
  int id = blockIdx.x * 256 + threadIdx.x;   // 192*192 = 36864
  int d = id / NC, c = id - d * NC;
  wvt[d * NC + c] = bf16r(w[c * WCOL + 2 * NDQ + d]);
}

// ---------------- KA: MFMA bf16 V-GEMM for ALL windows -> Vtmp bf16 ; fused window-mean ----------------
// 1024 threads = 16 waves; wave wv: win = wv>>2, d-quarter dq = wv&3 (48 dims).
__global__ __launch_bounds__(1024) void kA_vgemm(const float* __restrict__ x,
                                                 const unsigned short* __restrict__ wvt,
                                                 const float* __restrict__ bias,
                                                 unsigned short* __restrict__ vtmp,
                                                 float* __restrict__ xmean) {
  int b = blockIdx.y, g = blockIdx.x;   // g in [0,256)
  int m0 = g * 4;
  int wh = m0 >> 5, ww0 = m0 & 31;
  int t = threadIdx.x;

  __shared__ unsigned short Xs[16384];  // 32 KB: 4 win * 64 p * 128B
  __shared__ float part[32][64];        // 8 KB: [channel-in-chunk][gi] partial sums

  int L = t & 63, wv = t >> 6;
  int win = wv >> 2, dq = wv & 3;
  int col = L & 15, kg = L >> 4;

  f32x4 acc[4][3];
#pragma unroll
  for (int dt = 0; dt < 3; ++dt) {
    float bv = bias[2 * NDQ + dq * 48 + dt * 16 + col];
    f32x4 bi = {bv, bv, bv, bv};
#pragma unroll
    for (int pt = 0; pt < 4; ++pt) acc[pt][dt] = bi;
  }

  int cp = t & 15, gi = t >> 4;
  int r = gi >> 3, w4 = gi & 7;
  int winS = w4 >> 1;
  int pS = r * 8 + (w4 & 1) * 4;
  const float* xb = x + (size_t)(b * NC) * (HW * HW) + (size_t)(wh * 8 + r) * HW + ww0 * 8 + w4 * 4;

  // reduction-thread identity (t<128): window rw, channel-in-chunk rc
  int rw = (t >> 5) & 3, rc = t & 31;

  for (int cc = 0; cc < 6; ++cc) {
    const float* pl = xb + (size_t)(cc * 32 + cp * 2) * (HW * HW);
    float4 va = *(const float4*)pl;
    float4 vb = *(const float4*)(pl + HW * HW);
    float fa[4] = {va.x, va.y, va.z, va.w};
    float fb[4] = {vb.x, vb.y, vb.z, vb.w};
#pragma unroll
    for (int i = 0; i < 4; ++i) {
      int p = pS + i;
      unsigned int pk = bf16pack(fa[i], fb[i]);
      *(unsigned int*)((char*)Xs + (winS * 8192 + p * 128 + ((cp * 4) ^ ((p & 7) << 4)))) = pk;
    }
    part[cp * 2][gi]     = fa[0] + fa[1] + fa[2] + fa[3];
    part[cp * 2 + 1][gi] = fb[0] + fb[1] + fb[2] + fb[3];
    __syncthreads();

    // fused window-mean: 128 threads, deterministic fixed-order 16-way sum
    if (t < 128) {
      float s = 0.0f;
#pragma unroll
      for (int rr = 0; rr < 8; ++rr) {
        s += part[rc][rr * 8 + 2 * rw];
        s += part[rc][rr * 8 + 2 * rw + 1];
      }
      xmean[(size_t)(b * NWIN + m0 + rw) * NC + cc * 32 + rc] = s * (1.0f / 64.0f);
    }

    bf16x8 Bf[3];
#pragma unroll
    for (int dt = 0; dt < 3; ++dt)
      Bf[dt] = *(const bf16x8*)(wvt + (size_t)(dq * 48 + dt * 16 + col) * NC + cc * 32 + kg * 8);

#pragma unroll
    for (int pt = 0; pt < 4; ++pt) {
      int p = pt * 16 + col;
      bf16x8 Af = *(const bf16x8*)((const char*)Xs +
                    (win * 8192 + p * 128 + ((kg * 16) ^ ((p & 7) << 4))));
      acc[pt][0] = __builtin_amdgcn_mfma_f32_16x16x32_bf16(Af, Bf[0], acc[pt][0], 0, 0, 0);
      acc[pt][1] = __builtin_amdgcn_mfma_f32_16x16x32_bf16(Af, Bf[1], acc[pt][1], 0, 0, 0);
      acc[pt][2] = __builtin_amdgcn_mfma_f32_16x16x32_bf16(Af, Bf[2], acc[pt][2], 0, 0, 0);
    }
    __syncthreads();
  }

  unsigned short* dst = vtmp + (size_t)(b * NWIN + m0 + win) * (SHW * NC) + dq * 48 + col;
#pragma unroll
  for (int pt = 0; pt < 4; ++pt) {
#pragma unroll
    for (int rr = 0; rr < 4; ++rr) {
      unsigned short* dp = dst + (size_t)(pt * 16 + kg * 4 + rr) * NC;
      dp[0]  = bf16r(acc[pt][0][rr]);
      dp[16] = bf16r(acc[pt][1][rr]);
      dp[32] = bf16r(acc[pt][2][rr]);
    }
  }
}

// ---------------- K2: q_win (scaled) and k_win^T (round-7 proven form) ----------------
__global__ __launch_bounds__(192) void k2_qk(const float* __restrict__ xmean,
                                             const float* __restrict__ w,
                                             const float* __restrict__ bias,
                                             float* __restrict__ qw,
                                             float* __restrict__ kwT) {
  int b = blockIdx.y, n = blockIdx.x;
  int d = threadIdx.x;
  __shared__ float xs[NC];
  xs[d] = xmean[(size_t)(b * NWIN + n) * NC + d];
  __syncthreads();
  double aq = 0.0, ak = 0.0;
  for (int c = 0; c < NC; ++c) {
    double xc = (double)xs[c];
    aq += xc * (double)w[c * WCOL + d];
    ak += xc * (double)w[c * WCOL + NDQ + d];
  }
  const float scale = 0.0721687836487032f;
  float qv = (float)aq + bias[d];
  float kv = (float)ak + bias[NDQ + d];
  qw[(size_t)(b * NWIN + n) * NC + d] = qv * scale;
  kwT[(size_t)b * NC * NWIN + (size_t)d * NWIN + n] = kv;
}

// ---------------- K3: 8 logit rows per block (512 thr), per-wave top-4 ----------------
__global__ __launch_bounds__(512) void k3_topk(const float* __restrict__ qw,
                                               const float* __restrict__ kwT,
                                               int* __restrict__ topk) {
  int b = blockIdx.y, n0 = blockIdx.x * 8;
  int t = threadIdx.x;
  __shared__ float qs[8][NC];
  __shared__ float lg[8][NWIN];
#pragma unroll
  for (int i = 0; i < 3; ++i) {
    int l = i * 512 + t;
    int r = l / NC, c = l - r * NC;
    qs[r][c] = qw[(size_t)(b * NWIN + n0 + r) * NC + c];
  }
  __syncthreads();

  double acc[8][2];
#pragma unroll
  for (int r = 0; r < 8; ++r) { acc[r][0] = 0.0; acc[r][1] = 0.0; }

  const float* kb = kwT + (size_t)b * NC * NWIN;
#pragma unroll 2
  for (int c = 0; c < NC; ++c) {
    float2 kv = *(const float2*)(kb + (size_t)c * NWIN + t * 2);
    double k0 = (double)kv.x, k1 = (double)kv.y;
#pragma unroll
    for (int r = 0; r < 8; ++r) {
      double q = (double)qs[r][c];
      acc[r][0] += q * k0;
      acc[r][1] += q * k1;
    }
  }
#pragma unroll
  for (int r = 0; r < 8; ++r) {
    lg[r][t * 2]     = (float)acc[r][0];
    lg[r][t * 2 + 1] = (float)acc[r][1];
  }
  __syncthreads();

  int wave = t >> 6, lane = t & 63;
  int r = wave;  // 8 waves, one row each
  float v4[4];
  int   i4[4];
#pragma unroll
  for (int j = 0; j < 4; ++j) { v4[j] = -INFINITY; i4[j] = 0x7fffffff; }
  for (int i = 0; i < 16; ++i) {
    int idx = i * 64 + lane;
    float v = lg[r][idx];
    if (v > v4[3] || (v == v4[3] && idx < i4[3])) {
      v4[3] = v; i4[3] = idx;
#pragma unroll
      for (int j = 3; j > 0; --j) {
        if (v4[j] > v4[j-1] || (v4[j] == v4[j-1] && i4[j] < i4[j-1])) {
          float tv = v4[j]; v4[j] = v4[j-1]; v4[j-1] = tv;
          int ti = i4[j]; i4[j] = i4[j-1]; i4[j-1] = ti;
        }
      }
    }
  }
  for (int m = 1; m < 64; m <<= 1) {
    float ov[4]; int oi[4];
#pragma unroll
    for (int j = 0; j < 4; ++j) { ov[j] = __shfl_xor(v4[j], m); oi[j] = __shfl_xor(i4[j], m); }
    float nv[4]; int ni[4];
    int ia = 0, ib = 0;
#pragma unroll
    for (int j = 0; j < 4; ++j) {
      bool ta = (v4[ia] > ov[ib]) || (v4[ia] == ov[ib] && i4[ia] < oi[ib]);
      if (ta) { nv[j] = v4[ia]; ni[j] = i4[ia]; ++ia; }
      else    { nv[j] = ov[ib]; ni[j] = oi[ib]; ++ib; }
    }
#pragma unroll
    for (int j = 0; j < 4; ++j) { v4[j] = nv[j]; i4[j] = ni[j]; }
  }
  if (lane == 0) {
    int n = n0 + r;
#pragma unroll
    for (int k = 0; k < 4; ++k)
      topk[(size_t)(b * NWIN + n) * 4 + k] = i4[k];
  }
}

// ---------------- KB: gather+convert out[slot] = f32(Vtmp[b, topk[slot]]) ----------------
__global__ __launch_bounds__(256) void kB_gather(const unsigned short* __restrict__ vtmp,
                                                 const int* __restrict__ topk,
                                                 float* __restrict__ out) {
  int id = blockIdx.x;            // 8192 = b*4096 + n*4 + k
  int b = id >> 12;
  int m = topk[id];
  const unsigned short* src = vtmp + (size_t)(b * NWIN + m) * (SHW * NC);
  float* dst = out + (size_t)id * (SHW * NC);
  int t = threadIdx.x;
#pragma unroll
  for (int i = 0; i < 6; ++i) {
    int u = i * 256 + t;          // 1536 units of 8 bf16
    uint4 v = *(const uint4*)(src + u * 8);
    float4 a, c;
    a.x = __builtin_bit_cast(float, v.x << 16);
    a.y = __builtin_bit_cast(float, v.x & 0xffff0000u);
    a.z = __builtin_bit_cast(float, v.y << 16);
    a.w = __builtin_bit_cast(float, v.y & 0xffff0000u);
    c.x = __builtin_bit_cast(float, v.z << 16);
    c.y = __builtin_bit_cast(float, v.z & 0xffff0000u);
    c.z = __builtin_bit_cast(float, v.w << 16);
    c.w = __builtin_bit_cast(float, v.w & 0xffff0000u);
    *(float4*)(dst + u * 8)     = a;
    *(float4*)(dst + u * 8 + 4) = c;
  }
}

extern "C" void kernel_launch(void* const* d_in, const int* in_sizes, int n_in,
                              void* d_out, int out_size, void* d_ws, size_t ws_size,
                              hipStream_t stream) {
  const float* x    = (const float*)d_in[0];
  const float* w    = (const float*)d_in[1];
  const float* bias = (const float*)d_in[2];
  float* out = (float*)d_out;

  unsigned short* vtmp = (unsigned short*)d_ws;          // 2*1024*64*192 bf16 = 50 MB
  float* xmean = (float*)(vtmp + (size_t)25165824);      // 2*1024*192
  float* qw    = xmean + 393216;
  float* kwT   = qw + 393216;
  int*   topk  = (int*)(kwT + 393216);                   // 2*1024*4
  unsigned short* wvt = (unsigned short*)(topk + 8192);  // 192*192 bf16

  k0_wvt<<<144, 256, 0, stream>>>(w, wvt);
  kA_vgemm<<<dim3(256, 2), 1024, 0, stream>>>(x, wvt, bias, vtmp, xmean);
  k2_qk<<<dim3(1024, 2), 192, 0, stream>>>(xmean, w, bias, qw, kwT);
  k3_topk<<<dim3(128, 2), 512, 0, stream>>>(qw, kwT, topk);
  kB_gather<<<8192, 256, 0, stream>>>(vtmp, topk, out);
}

// Round 12
// 231.684 us; speedup vs baseline: 1.3530x; 1.0024x over previous
//
#include <hip/hip_runtime.h>
#include <hip/hip_bf16.h>
#include <math.h>

// x: (2, 192, 256, 256) f32 ; w_qkv: (192, 576) ; b_qkv: (576,)
// windows: 32x32 = 1024 per batch, 8x8=64 pixels each
// out: (2, 1024, 4, 64, 192) f32
#define NB   2
#define NC   192
#define HW   256
#define NWIN 1024
#define SHW  64
#define NDQ  192
#define WCOL 576

typedef short bf16x8 __attribute__((ext_vector_type(8)));
typedef float f32x4  __attribute__((ext_vector_type(4)));

__device__ inline unsigned int bf16pack(float a, float b) {
  unsigned int ua = __builtin_bit_cast(unsigned int, a);
  ua += 0x7fffu + ((ua >> 16) & 1u);
  unsigned int ub = __builtin_bit_cast(unsigned int, b);
  ub += 0x7fffu + ((ub >> 16) & 1u);
  return (ua >> 16) | (ub & 0xffff0000u);
}

__device__ inline unsigned short bf16r(float a) {
  unsigned int ua = __builtin_bit_cast(unsigned int, a);
  ua += 0x7fffu + ((ua >> 16) & 1u);
  return (unsigned short)(ua >> 16);
}

// ---------------- K0: precompute WvT bf16 [d][c] ----------------
__global__ __launch_bounds__(256) void k0_wvt(const float* __restrict__ w,
                                              unsigned short* __restrict__ wvt) {
  int id = blockIdx.x * 256 + threadIdx.x;   // 192*192 = 36864
  int d = id / NC, c = id - d * NC;
  wvt[d * NC + c] = bf16r(w[c * WCOL + 2 * NDQ + d]);
}

// ---------------- KA: V-GEMM (MFMA) + fused window-mean + fused q/k projection ----------------
// 1024 threads = 16 waves; wave wv: win = wv>>2, d-quarter dq = wv&3 (48 dims).
__global__ __launch_bounds__(1024) void kA_vgemm(const float* __restrict__ x,
                                                 const unsigned short* __restrict__ wvt,
                                                 const float* __restrict__ w,
                                                 const float* __restrict__ bias,
                                                 unsigned short* __restrict__ vtmp,
                                                 float* __restrict__ qw,
                                                 float* __restrict__ kwT) {
  int b = blockIdx.y, g = blockIdx.x;   // g in [0,256)
  int m0 = g * 4;
  int wh = m0 >> 5, ww0 = m0 & 31;
  int t = threadIdx.x;

  __shared__ unsigned short Xs[16384];  // 32 KB: 4 win * 64 p * 128B
  __shared__ float part[32][64];        // 8 KB: [channel-in-chunk][gi] partials
  __shared__ float xmLds[4][NC];        // 3 KB: per-window mean (f32)

  int L = t & 63, wv = t >> 6;
  int win = wv >> 2, dq = wv & 3;
  int col = L & 15, kg = L >> 4;

  f32x4 acc[4][3];
#pragma unroll
  for (int dt = 0; dt < 3; ++dt) {
    float bv = bias[2 * NDQ + dq * 48 + dt * 16 + col];
    f32x4 bi = {bv, bv, bv, bv};
#pragma unroll
    for (int pt = 0; pt < 4; ++pt) acc[pt][dt] = bi;
  }

  int cp = t & 15, gi = t >> 4;
  int r = gi >> 3, w4 = gi & 7;
  int winS = w4 >> 1;
  int pS = r * 8 + (w4 & 1) * 4;
  const float* xb = x + (size_t)(b * NC) * (HW * HW) + (size_t)(wh * 8 + r) * HW + ww0 * 8 + w4 * 4;

  // reduction-thread identity (t<128): window rw, channel-in-chunk rc
  int rw = (t >> 5) & 3, rc = t & 31;

  for (int cc = 0; cc < 6; ++cc) {
    const float* pl = xb + (size_t)(cc * 32 + cp * 2) * (HW * HW);
    float4 va = *(const float4*)pl;
    float4 vb = *(const float4*)(pl + HW * HW);
    float fa[4] = {va.x, va.y, va.z, va.w};
    float fb[4] = {vb.x, vb.y, vb.z, vb.w};
#pragma unroll
    for (int i = 0; i < 4; ++i) {
      int p = pS + i;
      unsigned int pk = bf16pack(fa[i], fb[i]);
      *(unsigned int*)((char*)Xs + (winS * 8192 + p * 128 + ((cp * 4) ^ ((p & 7) << 4)))) = pk;
    }
    part[cp * 2][gi]     = fa[0] + fa[1] + fa[2] + fa[3];
    part[cp * 2 + 1][gi] = fb[0] + fb[1] + fb[2] + fb[3];
    __syncthreads();

    // fused window-mean: 128 threads, deterministic fixed-order 16-way sum
    if (t < 128) {
      float s = 0.0f;
#pragma unroll
      for (int rr = 0; rr < 8; ++rr) {
        s += part[rc][rr * 8 + 2 * rw];
        s += part[rc][rr * 8 + 2 * rw + 1];
      }
      xmLds[rw][cc * 32 + rc] = s * (1.0f / 64.0f);
    }

    bf16x8 Bf[3];
#pragma unroll
    for (int dt = 0; dt < 3; ++dt)
      Bf[dt] = *(const bf16x8*)(wvt + (size_t)(dq * 48 + dt * 16 + col) * NC + cc * 32 + kg * 8);

#pragma unroll
    for (int pt = 0; pt < 4; ++pt) {
      int p = pt * 16 + col;
      bf16x8 Af = *(const bf16x8*)((const char*)Xs +
                    (win * 8192 + p * 128 + ((kg * 16) ^ ((p & 7) << 4))));
      acc[pt][0] = __builtin_amdgcn_mfma_f32_16x16x32_bf16(Af, Bf[0], acc[pt][0], 0, 0, 0);
      acc[pt][1] = __builtin_amdgcn_mfma_f32_16x16x32_bf16(Af, Bf[1], acc[pt][1], 0, 0, 0);
      acc[pt][2] = __builtin_amdgcn_mfma_f32_16x16x32_bf16(Af, Bf[2], acc[pt][2], 0, 0, 0);
    }
    __syncthreads();
  }

  // ---- V tile store (bf16): D layout col=lane&15, row=(lane>>4)*4+reg ----
  unsigned short* dst = vtmp + (size_t)(b * NWIN + m0 + win) * (SHW * NC) + dq * 48 + col;
#pragma unroll
  for (int pt = 0; pt < 4; ++pt) {
#pragma unroll
    for (int rr = 0; rr < 4; ++rr) {
      unsigned short* dp = dst + (size_t)(pt * 16 + kg * 4 + rr) * NC;
      dp[0]  = bf16r(acc[pt][0][rr]);
      dp[16] = bf16r(acc[pt][1][rr]);
      dp[32] = bf16r(acc[pt][2][rr]);
    }
  }

  // ---- fused q/k projection (bit-identical to the former k2) ----
  // 1536 outputs: win(4) x d(384). f64 accumulate, c ascending.
  for (int o = t; o < 1536; o += 1024) {
    int winq = o >> 9 << 1 | 0;            // placeholder, recomputed below
    winq = o / 384;
    int d = o - winq * 384;
    const float* xr = xmLds[winq];
    double a = 0.0;
    for (int c = 0; c < NC; ++c)
      a += (double)xr[c] * (double)w[c * WCOL + d];
    float bv = bias[d];
    int n = m0 + winq;
    if (d < NDQ) {
      float qv = (float)a + bv;
      qw[(size_t)(b * NWIN + n) * NC + d] = qv * 0.0721687836487032f;
    } else {
      float kv = (float)a + bv;
      kwT[(size_t)b * NC * NWIN + (size_t)(d - NDQ) * NWIN + n] = kv;
    }
  }
}

// ---------------- K3: 8 logit rows per block (512 thr), per-wave top-4 ----------------
__global__ __launch_bounds__(512) void k3_topk(const float* __restrict__ qw,
                                               const float* __restrict__ kwT,
                                               int* __restrict__ topk) {
  int b = blockIdx.y, n0 = blockIdx.x * 8;
  int t = threadIdx.x;
  __shared__ float qs[8][NC];
  __shared__ float lg[8][NWIN];
#pragma unroll
  for (int i = 0; i < 3; ++i) {
    int l = i * 512 + t;
    int r = l / NC, c = l - r * NC;
    qs[r][c] = qw[(size_t)(b * NWIN + n0 + r) * NC + c];
  }
  __syncthreads();

  double acc[8][2];
#pragma unroll
  for (int r = 0; r < 8; ++r) { acc[r][0] = 0.0; acc[r][1] = 0.0; }

  const float* kb = kwT + (size_t)b * NC * NWIN;
#pragma unroll 2
  for (int c = 0; c < NC; ++c) {
    float2 kv = *(const float2*)(kb + (size_t)c * NWIN + t * 2);
    double k0 = (double)kv.x, k1 = (double)kv.y;
#pragma unroll
    for (int r = 0; r < 8; ++r) {
      double q = (double)qs[r][c];
      acc[r][0] += q * k0;
      acc[r][1] += q * k1;
    }
  }
#pragma unroll
  for (int r = 0; r < 8; ++r) {
    lg[r][t * 2]     = (float)acc[r][0];
    lg[r][t * 2 + 1] = (float)acc[r][1];
  }
  __syncthreads();

  int wave = t >> 6, lane = t & 63;
  int r = wave;  // 8 waves, one row each
  float v4[4];
  int   i4[4];
#pragma unroll
  for (int j = 0; j < 4; ++j) { v4[j] = -INFINITY; i4[j] = 0x7fffffff; }
  for (int i = 0; i < 16; ++i) {
    int idx = i * 64 + lane;
    float v = lg[r][idx];
    if (v > v4[3] || (v == v4[3] && idx < i4[3])) {
      v4[3] = v; i4[3] = idx;
#pragma unroll
      for (int j = 3; j > 0; --j) {
        if (v4[j] > v4[j-1] || (v4[j] == v4[j-1] && i4[j] < i4[j-1])) {
          float tv = v4[j]; v4[j] = v4[j-1]; v4[j-1] = tv;
          int ti = i4[j]; i4[j] = i4[j-1]; i4[j-1] = ti;
        }
      }
    }
  }
  for (int m = 1; m < 64; m <<= 1) {
    float ov[4]; int oi[4];
#pragma unroll
    for (int j = 0; j < 4; ++j) { ov[j] = __shfl_xor(v4[j], m); oi[j] = __shfl_xor(i4[j], m); }
    float nv[4]; int ni[4];
    int ia = 0, ib = 0;
#pragma unroll
    for (int j = 0; j < 4; ++j) {
      bool ta = (v4[ia] > ov[ib]) || (v4[ia] == ov[ib] && i4[ia] < oi[ib]);
      if (ta) { nv[j] = v4[ia]; ni[j] = i4[ia]; ++ia; }
      else    { nv[j] = ov[ib]; ni[j] = oi[ib]; ++ib; }
    }
#pragma unroll
    for (int j = 0; j < 4; ++j) { v4[j] = nv[j]; i4[j] = ni[j]; }
  }
  if (lane == 0) {
    int n = n0 + r;
#pragma unroll
    for (int k = 0; k < 4; ++k)
      topk[(size_t)(b * NWIN + n) * 4 + k] = i4[k];
  }
}

// ---------------- KB: gather+convert out[slot] = f32(Vtmp[b, topk[slot]]) ----------------
__global__ __launch_bounds__(256) void kB_gather(const unsigned short* __restrict__ vtmp,
                                                 const int* __restrict__ topk,
                                                 float* __restrict__ out) {
  int id = blockIdx.x;            // 8192 = b*4096 + n*4 + k
  int b = id >> 12;
  int m = topk[id];
  const unsigned short* src = vtmp + (size_t)(b * NWIN + m) * (SHW * NC);
  float* dst = out + (size_t)id * (SHW * NC);
  int t = threadIdx.x;
#pragma unroll
  for (int i = 0; i < 6; ++i) {
    int u = i * 256 + t;          // 1536 units of 8 bf16
    uint4 v = *(const uint4*)(src + u * 8);
    float4 a, c;
    a.x = __builtin_bit_cast(float, v.x << 16);
    a.y = __builtin_bit_cast(float, v.x & 0xffff0000u);
    a.z = __builtin_bit_cast(float, v.y << 16);
    a.w = __builtin_bit_cast(float, v.y & 0xffff0000u);
    c.x = __builtin_bit_cast(float, v.z << 16);
    c.y = __builtin_bit_cast(float, v.z & 0xffff0000u);
    c.z = __builtin_bit_cast(float, v.w << 16);
    c.w = __builtin_bit_cast(float, v.w & 0xffff0000u);
    *(float4*)(dst + u * 8)     = a;
    *(float4*)(dst + u * 8 + 4) = c;
  }
}

extern "C" void kernel_launch(void* const* d_in, const int* in_sizes, int n_in,
                              void* d_out, int out_size, void* d_ws, size_t ws_size,
                              hipStream_t stream) {
  const float* x    = (const float*)d_in[0];
  const float* w    = (const float*)d_in[1];
  const float* bias = (const float*)d_in[2];
  float* out = (float*)d_out;

  unsigned short* vtmp = (unsigned short*)d_ws;          // 2*1024*64*192 bf16 = 50 MB
  float* qw    = (float*)(vtmp + (size_t)25165824);      // 2*1024*192
  float* kwT   = qw + 393216;                            // 2*192*1024
  int*   topk  = (int*)(kwT + 393216);                   // 2*1024*4
  unsigned short* wvt = (unsigned short*)(topk + 8192);  // 192*192 bf16

  k0_wvt<<<144, 256, 0, stream>>>(w, wvt);
  kA_vgemm<<<dim3(256, 2), 1024, 0, stream>>>(x, wvt, w, bias, vtmp, qw, kwT);
  k3_topk<<<dim3(128, 2), 512, 0, stream>>>(qw, kwT, topk);
  kB_gather<<<8192, 256, 0, stream>>>(vtmp, topk, out);
}

// Round 13
// 230.523 us; speedup vs baseline: 1.3598x; 1.0050x over previous
//
#include <hip/hip_runtime.h>
#include <hip/hip_bf16.h>
#include <math.h>

// x: (2, 192, 256, 256) f32 ; w_qkv: (192, 576) ; b_qkv: (576,)
// windows: 32x32 = 1024 per batch, 8x8=64 pixels each
// out: (2, 1024, 4, 64, 192) f32
#define NB   2
#define NC   192
#define HW   256
#define NWIN 1024
#define SHW  64
#define NDQ  192
#define WCOL 576

typedef short bf16x8 __attribute__((ext_vector_type(8)));
typedef float f32x4  __attribute__((ext_vector_type(4)));

__device__ inline unsigned int bf16pack(float a, float b) {
  unsigned int ua = __builtin_bit_cast(unsigned int, a);
  ua += 0x7fffu + ((ua >> 16) & 1u);
  unsigned int ub = __builtin_bit_cast(unsigned int, b);
  ub += 0x7fffu + ((ub >> 16) & 1u);
  return (ua >> 16) | (ub & 0xffff0000u);
}

__device__ inline unsigned short bf16r(float a) {
  unsigned int ua = __builtin_bit_cast(unsigned int, a);
  ua += 0x7fffu + ((ua >> 16) & 1u);
  return (unsigned short)(ua >> 16);
}

// ---------------- K0: precompute WvT bf16 [d][c] ----------------
__global__ __launch_bounds__(256) void k0_wvt(const float* __restrict__ w,
                                              unsigned short* __restrict__ wvt) {
  int id = blockIdx.x * 256 + threadIdx.x;   // 192*192 = 36864
  int d = id / NC, c = id - d * NC;
  wvt[d * NC + c] = bf16r(w[c * WCOL + 2 * NDQ + d]);
}

// ---------------- KA: V-GEMM (MFMA) + fused window-mean + fused q/k projection ----------------
// 1024 threads = 16 waves; wave wv: win = wv>>2, d-quarter dq = wv&3 (48 dims).
__global__ __launch_bounds__(1024) void kA_vgemm(const float* __restrict__ x,
                                                 const unsigned short* __restrict__ wvt,
                                                 const float* __restrict__ w,
                                                 const float* __restrict__ bias,
                                                 unsigned short* __restrict__ vtmp,
                                                 float* __restrict__ qw,
                                                 float* __restrict__ kwT) {
  int b = blockIdx.y, g = blockIdx.x;   // g in [0,256)
  int m0 = g * 4;
  int wh = m0 >> 5, ww0 = m0 & 31;
  int t = threadIdx.x;

  __shared__ unsigned short Xs[16384];  // 32 KB: 4 win * 64 p * 128B
  __shared__ float part[32][64];        // 8 KB
  __shared__ float xmLds[4][NC];        // 3 KB

  int L = t & 63, wv = t >> 6;
  int win = wv >> 2, dq = wv & 3;
  int col = L & 15, kg = L >> 4;

  f32x4 acc[4][3];
#pragma unroll
  for (int dt = 0; dt < 3; ++dt) {
    float bv = bias[2 * NDQ + dq * 48 + dt * 16 + col];
    f32x4 bi = {bv, bv, bv, bv};
#pragma unroll
    for (int pt = 0; pt < 4; ++pt) acc[pt][dt] = bi;
  }

  int cp = t & 15, gi = t >> 4;
  int r = gi >> 3, w4 = gi & 7;
  int winS = w4 >> 1;
  int pS = r * 8 + (w4 & 1) * 4;
  const float* xb = x + (size_t)(b * NC) * (HW * HW) + (size_t)(wh * 8 + r) * HW + ww0 * 8 + w4 * 4;

  int rw = (t >> 5) & 3, rc = t & 31;

  for (int cc = 0; cc < 6; ++cc) {
    const float* pl = xb + (size_t)(cc * 32 + cp * 2) * (HW * HW);
    float4 va = *(const float4*)pl;
    float4 vb = *(const float4*)(pl + HW * HW);
    float fa[4] = {va.x, va.y, va.z, va.w};
    float fb[4] = {vb.x, vb.y, vb.z, vb.w};
#pragma unroll
    for (int i = 0; i < 4; ++i) {
      int p = pS + i;
      unsigned int pk = bf16pack(fa[i], fb[i]);
      *(unsigned int*)((char*)Xs + (winS * 8192 + p * 128 + ((cp * 4) ^ ((p & 7) << 4)))) = pk;
    }
    part[cp * 2][gi]     = fa[0] + fa[1] + fa[2] + fa[3];
    part[cp * 2 + 1][gi] = fb[0] + fb[1] + fb[2] + fb[3];
    __syncthreads();

    if (t < 128) {
      float s = 0.0f;
#pragma unroll
      for (int rr = 0; rr < 8; ++rr) {
        s += part[rc][rr * 8 + 2 * rw];
        s += part[rc][rr * 8 + 2 * rw + 1];
      }
      xmLds[rw][cc * 32 + rc] = s * (1.0f / 64.0f);
    }

    bf16x8 Bf[3];
#pragma unroll
    for (int dt = 0; dt < 3; ++dt)
      Bf[dt] = *(const bf16x8*)(wvt + (size_t)(dq * 48 + dt * 16 + col) * NC + cc * 32 + kg * 8);

#pragma unroll
    for (int pt = 0; pt < 4; ++pt) {
      int p = pt * 16 + col;
      bf16x8 Af = *(const bf16x8*)((const char*)Xs +
                    (win * 8192 + p * 128 + ((kg * 16) ^ ((p & 7) << 4))));
      acc[pt][0] = __builtin_amdgcn_mfma_f32_16x16x32_bf16(Af, Bf[0], acc[pt][0], 0, 0, 0);
      acc[pt][1] = __builtin_amdgcn_mfma_f32_16x16x32_bf16(Af, Bf[1], acc[pt][1], 0, 0, 0);
      acc[pt][2] = __builtin_amdgcn_mfma_f32_16x16x32_bf16(Af, Bf[2], acc[pt][2], 0, 0, 0);
    }
    __syncthreads();
  }

  // ---- V tile store (bf16): D layout col=lane&15, row=(lane>>4)*4+reg ----
  unsigned short* dst = vtmp + (size_t)(b * NWIN + m0 + win) * (SHW * NC) + dq * 48 + col;
#pragma unroll
  for (int pt = 0; pt < 4; ++pt) {
#pragma unroll
    for (int rr = 0; rr < 4; ++rr) {
      unsigned short* dp = dst + (size_t)(pt * 16 + kg * 4 + rr) * NC;
      dp[0]  = bf16r(acc[pt][0][rr]);
      dp[16] = bf16r(acc[pt][1][rr]);
      dp[32] = bf16r(acc[pt][2][rr]);
    }
  }

  // ---- fused q/k projection (bit-identical to the former k2) ----
  for (int o = t; o < 1536; o += 1024) {
    int winq = o / 384;
    int d = o - winq * 384;
    const float* xr = xmLds[winq];
    double a = 0.0;
    for (int c = 0; c < NC; ++c)
      a += (double)xr[c] * (double)w[c * WCOL + d];
    float bv = bias[d];
    int n = m0 + winq;
    if (d < NDQ) {
      float qv = (float)a + bv;
      qw[(size_t)(b * NWIN + n) * NC + d] = qv * 0.0721687836487032f;
    } else {
      float kv = (float)a + bv;
      kwT[(size_t)b * NC * NWIN + (size_t)(d - NDQ) * NWIN + n] = kv;
    }
  }
}

// ---------------- K3: 8 logit rows per block, 1024 thr (16 waves), per-wave top-4 ----------------
// Each thread: 2 cols x 4 rows (was 2x8) -> same f64 op order per (row,col) => bit-identical.
__global__ __launch_bounds__(1024) void k3_topk(const float* __restrict__ qw,
                                                const float* __restrict__ kwT,
                                                int* __restrict__ topk) {
  int b = blockIdx.y, n0 = blockIdx.x * 8;
  int t = threadIdx.x;
  __shared__ float qs[8][NC];
  __shared__ float lg[8][NWIN];
  for (int l = t; l < 8 * NC; l += 1024) {
    int r = l / NC, c = l - r * NC;
    qs[r][c] = qw[(size_t)(b * NWIN + n0 + r) * NC + c];
  }
  __syncthreads();

  int col2 = (t & 511) * 2;   // column pair
  int rg = (t >> 9) * 4;      // row group base (0 or 4)

  double acc[4][2];
#pragma unroll
  for (int r = 0; r < 4; ++r) { acc[r][0] = 0.0; acc[r][1] = 0.0; }

  const float* kb = kwT + (size_t)b * NC * NWIN;
#pragma unroll 2
  for (int c = 0; c < NC; ++c) {
    float2 kv = *(const float2*)(kb + (size_t)c * NWIN + col2);
    double k0 = (double)kv.x, k1 = (double)kv.y;
#pragma unroll
    for (int r = 0; r < 4; ++r) {
      double q = (double)qs[rg + r][c];
      acc[r][0] += q * k0;
      acc[r][1] += q * k1;
    }
  }
#pragma unroll
  for (int r = 0; r < 4; ++r) {
    lg[rg + r][col2]     = (float)acc[r][0];
    lg[rg + r][col2 + 1] = (float)acc[r][1];
  }
  __syncthreads();

  int wave = t >> 6, lane = t & 63;
  if (wave < 8) {
    int r = wave;  // one row per wave
    float v4[4];
    int   i4[4];
#pragma unroll
    for (int j = 0; j < 4; ++j) { v4[j] = -INFINITY; i4[j] = 0x7fffffff; }
    for (int i = 0; i < 16; ++i) {
      int idx = i * 64 + lane;
      float v = lg[r][idx];
      if (v > v4[3] || (v == v4[3] && idx < i4[3])) {
        v4[3] = v; i4[3] = idx;
#pragma unroll
        for (int j = 3; j > 0; --j) {
          if (v4[j] > v4[j-1] || (v4[j] == v4[j-1] && i4[j] < i4[j-1])) {
            float tv = v4[j]; v4[j] = v4[j-1]; v4[j-1] = tv;
            int ti = i4[j]; i4[j] = i4[j-1]; i4[j-1] = ti;
          }
        }
      }
    }
    for (int m = 1; m < 64; m <<= 1) {
      float ov[4]; int oi[4];
#pragma unroll
      for (int j = 0; j < 4; ++j) { ov[j] = __shfl_xor(v4[j], m); oi[j] = __shfl_xor(i4[j], m); }
      float nv[4]; int ni[4];
      int ia = 0, ib = 0;
#pragma unroll
      for (int j = 0; j < 4; ++j) {
        bool ta = (v4[ia] > ov[ib]) || (v4[ia] == ov[ib] && i4[ia] < oi[ib]);
        if (ta) { nv[j] = v4[ia]; ni[j] = i4[ia]; ++ia; }
        else    { nv[j] = ov[ib]; ni[j] = oi[ib]; ++ib; }
      }
#pragma unroll
      for (int j = 0; j < 4; ++j) { v4[j] = nv[j]; i4[j] = ni[j]; }
    }
    if (lane == 0) {
      int n = n0 + r;
#pragma unroll
      for (int k = 0; k < 4; ++k)
        topk[(size_t)(b * NWIN + n) * 4 + k] = i4[k];
    }
  }
}

// ---------------- KB: gather+convert, 512 thr (8 waves) per slot ----------------
__global__ __launch_bounds__(512) void kB_gather(const unsigned short* __restrict__ vtmp,
                                                 const int* __restrict__ topk,
                                                 float* __restrict__ out) {
  int id = blockIdx.x;            // 8192 = b*4096 + n*4 + k
  int b = id >> 12;
  int m = topk[id];
  const unsigned short* src = vtmp + (size_t)(b * NWIN + m) * (SHW * NC);
  float* dst = out + (size_t)id * (SHW * NC);
  int t = threadIdx.x;
#pragma unroll
  for (int i = 0; i < 3; ++i) {
    int u = i * 512 + t;          // 1536 units of 8 bf16
    uint4 v = *(const uint4*)(src + u * 8);
    float4 a, c;
    a.x = __builtin_bit_cast(float, v.x << 16);
    a.y = __builtin_bit_cast(float, v.x & 0xffff0000u);
    a.z = __builtin_bit_cast(float, v.y << 16);
    a.w = __builtin_bit_cast(float, v.y & 0xffff0000u);
    c.x = __builtin_bit_cast(float, v.z << 16);
    c.y = __builtin_bit_cast(float, v.z & 0xffff0000u);
    c.z = __builtin_bit_cast(float, v.w << 16);
    c.w = __builtin_bit_cast(float, v.w & 0xffff0000u);
    *(float4*)(dst + u * 8)     = a;
    *(float4*)(dst + u * 8 + 4) = c;
  }
}

extern "C" void kernel_launch(void* const* d_in, const int* in_sizes, int n_in,
                              void* d_out, int out_size, void* d_ws, size_t ws_size,
                              hipStream_t stream) {
  const float* x    = (const float*)d_in[0];
  const float* w    = (const float*)d_in[1];
  const float* bias = (const float*)d_in[2];
  float* out = (float*)d_out;

  unsigned short* vtmp = (unsigned short*)d_ws;          // 2*1024*64*192 bf16 = 50 MB
  float* qw    = (float*)(vtmp + (size_t)25165824);      // 2*1024*192
  float* kwT   = qw + 393216;                            // 2*192*1024
  int*   topk  = (int*)(kwT + 393216);                   // 2*1024*4
  unsigned short* wvt = (unsigned short*)(topk + 8192);  // 192*192 bf16

  k0_wvt<<<144, 256, 0, stream>>>(w, wvt);
  kA_vgemm<<<dim3(256, 2), 1024, 0, stream>>>(x, wvt, w, bias, vtmp, qw, kwT);
  k3_topk<<<dim3(128, 2), 1024, 0, stream>>>(qw, kwT, topk);
  kB_gather<<<8192, 512, 0, stream>>>(vtmp, topk, out);
}